// Round 1
// baseline (199.820 us; speedup 1.0000x reference)
//
#include <hip/hip_runtime.h>

#define HH 64
#define WW 64
#define CC 256
#define DD 64    // C/R
#define EE 144   // K*K*G
#define NPIX 32768

// ws layout (floats):
//   [0, 16384)      W1fT[d][c]  (BN-scale folded, transposed)
//   [16384, 16448)  b1f[d]      (BN-folded bias)
//   [16448, 25664)  W2T[e][d]
#define WS_W1T 0
#define WS_B1F 16384
#define WS_W2T 16448

__global__ __launch_bounds__(256) void fold_kernel(
        const float* __restrict__ W1, const float* __restrict__ b1,
        const float* __restrict__ gamma, const float* __restrict__ beta,
        const float* __restrict__ mean, const float* __restrict__ var,
        const float* __restrict__ W2, float* __restrict__ ws) {
    int tid = blockIdx.x * 256 + threadIdx.x;
    if (tid < 16384) {
        int d = tid >> 8, c = tid & 255;
        float scale = gamma[d] * rsqrtf(var[d] + 1e-3f);
        ws[WS_W1T + tid] = W1[c * 64 + d] * scale;   // W1fT[d][c]
    }
    if (tid < 9216) {
        int e = tid >> 6, d = tid & 63;
        ws[WS_W2T + tid] = W2[d * 144 + e];          // W2T[e][d]
    }
    if (tid < 64) {
        float scale = gamma[tid] * rsqrtf(var[tid] + 1e-3f);
        ws[WS_B1F + tid] = (b1[tid] - mean[tid]) * scale + beta[tid];
    }
}

// One block: 32 pixels. 4 waves; wave w owns pixels w*8..w*8+7, lane = d (GEMM1)
// then lanes cover e in {lane, lane+64, lane+128} (GEMM2).
__global__ __launch_bounds__(256) void kergen_kernel(
        const float* __restrict__ x, const float* __restrict__ ws,
        const float* __restrict__ b2, float* __restrict__ ker_out) {
    __shared__ float xs[32 * 256];   // 32 KB
    __shared__ float hs[32 * 64];    // 8 KB
    const int t = threadIdx.x;
    const int p0 = blockIdx.x * 32;

    // stage x tile (contiguous, coalesced float4)
    {
        const float4* xg = (const float4*)(x + (size_t)p0 * 256);
        float4* xl = (float4*)xs;
        #pragma unroll
        for (int i = 0; i < 8; i++) xl[t + i * 256] = xg[t + i * 256];
    }
    __syncthreads();

    const int wave = t >> 6, lane = t & 63;
    const int pb = wave * 8;

    // ---- GEMM1: h[p][d] = relu(BN(x[p]·W1[:,d])) ----
    {
        const int d = lane;
        float acc[8];
        const float bb = ws[WS_B1F + d];
        #pragma unroll
        for (int p = 0; p < 8; p++) acc[p] = bb;
        const float4* w1 = (const float4*)(ws + WS_W1T + d * 256);
        #pragma unroll 4
        for (int c4 = 0; c4 < 64; c4++) {
            float4 w = w1[c4];
            #pragma unroll
            for (int p = 0; p < 8; p++) {
                float4 xv = ((const float4*)(xs + (pb + p) * 256))[c4];
                acc[p] += w.x * xv.x + w.y * xv.y + w.z * xv.z + w.w * xv.w;
            }
        }
        #pragma unroll
        for (int p = 0; p < 8; p++) hs[(pb + p) * 64 + d] = fmaxf(acc[p], 0.f);
    }
    __syncthreads();

    // ---- GEMM2: ker[p][e] = h[p]·W2[:,e] + b2[e] ----
    {
        const int e0 = lane;
        const int e1 = lane + 64;
        const int e2 = (lane < 16) ? (lane + 128) : 143;  // clamp (discarded if >=16)
        const float4* w0 = (const float4*)(ws + WS_W2T + e0 * 64);
        const float4* w1_ = (const float4*)(ws + WS_W2T + e1 * 64);
        const float4* w2_ = (const float4*)(ws + WS_W2T + e2 * 64);
        const float bb0 = b2[e0], bb1 = b2[e1], bb2 = b2[e2];
        for (int p = 0; p < 8; p++) {
            const float4* hv = (const float4*)(hs + (pb + p) * 64);
            float a0 = bb0, a1 = bb1, a2 = bb2;
            #pragma unroll 4
            for (int d4 = 0; d4 < 16; d4++) {
                float4 h4 = hv[d4];
                float4 wa = w0[d4];
                float4 wb = w1_[d4];
                float4 wc = w2_[d4];
                a0 += wa.x * h4.x + wa.y * h4.y + wa.z * h4.z + wa.w * h4.w;
                a1 += wb.x * h4.x + wb.y * h4.y + wb.z * h4.z + wb.w * h4.w;
                a2 += wc.x * h4.x + wc.y * h4.y + wc.z * h4.z + wc.w * h4.w;
            }
            float* kerp = ker_out + (size_t)(p0 + pb + p) * 144;
            kerp[e0] = a0;
            kerp[e1] = a1;
            if (lane < 16) kerp[lane + 128] = a2;
        }
    }
}

// One block: 4 pixels (one per wave), lane covers 4 channels via float4.
__global__ __launch_bounds__(256) void invol_kernel(
        const float* __restrict__ x, const float* __restrict__ ker,
        float* __restrict__ out) {
    __shared__ float ks[4 * 144];
    const int t = threadIdx.x;
    const int p0 = blockIdx.x * 4;   // 4 pixels, same (b,i) row (4 | W)
    for (int idx = t; idx < 576; idx += 256)
        ks[idx] = ker[(size_t)p0 * 144 + idx];
    __syncthreads();

    const int wave = t >> 6, lane = t & 63;
    const int pix = p0 + wave;
    const int bi = pix >> 6;     // b*64 + i
    const int j  = pix & 63;
    const int i  = bi & 63;

    float4 o = {0.f, 0.f, 0.f, 0.f};
    const float* kp = ks + wave * 144 + (lane & 3) * 4;
    #pragma unroll
    for (int k = 0; k < 9; k++) {
        const int di = k / 3 - 1, dj = k % 3 - 1;
        const int row = i + di, col = j + dj;
        float4 xv = {0.f, 0.f, 0.f, 0.f};
        if ((unsigned)row < 64u && (unsigned)col < 64u) {
            xv = ((const float4*)x)[(size_t)((bi + di) * 64 + col) * 64 + lane];
        }
        float4 kv = *(const float4*)(kp + k * 16);
        o.x += kv.x * xv.x;
        o.y += kv.y * xv.y;
        o.z += kv.z * xv.z;
        o.w += kv.w * xv.w;
    }
    ((float4*)out)[(size_t)pix * 64 + lane] = o;
}

extern "C" void kernel_launch(void* const* d_in, const int* in_sizes, int n_in,
                              void* d_out, int out_size, void* d_ws, size_t ws_size,
                              hipStream_t stream) {
    const float* x     = (const float*)d_in[0];
    const float* W1    = (const float*)d_in[1];
    const float* b1    = (const float*)d_in[2];
    const float* gamma = (const float*)d_in[3];
    const float* beta  = (const float*)d_in[4];
    const float* mmean = (const float*)d_in[5];
    const float* mvar  = (const float*)d_in[6];
    const float* W2    = (const float*)d_in[7];
    const float* b2    = (const float*)d_in[8];

    float* out_main = (float*)d_out;                     // (B,H,W,C) = 8388608 floats
    float* out_ker  = (float*)d_out + 8388608;           // (B,H,W,144) = 4718592 floats
    float* ws       = (float*)d_ws;

    fold_kernel<<<64, 256, 0, stream>>>(W1, b1, gamma, beta, mmean, mvar, W2, ws);
    kergen_kernel<<<NPIX / 32, 256, 0, stream>>>(x, ws, b2, out_ker);
    invol_kernel<<<NPIX / 4, 256, 0, stream>>>(x, out_ker, out_main);
}

// Round 3
// 43.718 us; speedup vs baseline: 4.5706x; 4.5706x over previous
//
#include <hip/hip_runtime.h>

typedef __attribute__((ext_vector_type(8))) short bf16x8;
typedef __attribute__((ext_vector_type(4))) float f32x4;

#define NPIX 32768

// ws byte layout:
//   [0, 32768)      W1fT bf16 [64 d][256 c]   (BN scale folded)
//   [32768, 51200)  W2T  bf16 [144 e][64 d]
//   [51200, 51456)  b1f  f32  [64]            (BN-folded bias)
// h (bf16 [32768][64]) is stored in the out_main region of d_out (scratch;
// fully overwritten by invol_kernel afterwards).

__device__ __forceinline__ ushort f2bf(float f) {
    union { float f; unsigned u; } v; v.f = f;
    unsigned r = (v.u + 0x7FFFu + ((v.u >> 16) & 1u)) >> 16;  // RNE
    return (ushort)r;
}

__global__ __launch_bounds__(256) void fold_kernel(
        const float* __restrict__ W1, const float* __restrict__ b1,
        const float* __restrict__ gamma, const float* __restrict__ beta,
        const float* __restrict__ mean, const float* __restrict__ var,
        const float* __restrict__ W2, void* __restrict__ ws) {
    ushort* w1t = (ushort*)ws;
    ushort* w2t = (ushort*)ws + 16384;
    float*  b1f = (float*)((char*)ws + 51200);
    int tid = blockIdx.x * 256 + threadIdx.x;
    if (tid < 16384) {
        int d = tid >> 8, c = tid & 255;
        float scale = gamma[d] * rsqrtf(var[d] + 1e-3f);
        w1t[tid] = f2bf(W1[c * 64 + d] * scale);       // W1fT[d][c]
    }
    if (tid < 9216) {
        int e = tid >> 6, d = tid & 63;
        w2t[tid] = f2bf(W2[d * 144 + e]);              // W2T[e][d]
    }
    if (tid < 64) {
        float scale = gamma[tid] * rsqrtf(var[tid] + 1e-3f);
        b1f[tid] = (b1[tid] - mean[tid]) * scale + beta[tid];
    }
}

// GEMM1: h[p][d] = relu(x[p][c] * W1f[c][d] + b1f[d]), bf16 MFMA.
// Block = 64 pixels, 4 waves; wave owns 16 px x 64 d (4 d-tiles).
__global__ __launch_bounds__(256) void gemm1_kernel(
        const float* __restrict__ x, const void* __restrict__ ws,
        ushort* __restrict__ h) {
    __shared__ __align__(16) ushort xs[64 * 256];   // 32 KB, 512 B rows, swizzled
    __shared__ __align__(16) ushort w1s[64 * 256];  // 32 KB
    const int t = threadIdx.x;
    const int p0 = blockIdx.x * 64;
    const ushort* w1t = (const ushort*)ws;
    const float*  b1f = (const float*)((const char*)ws + 51200);

    // stage x tile: f32 -> bf16, XOR-swizzled rows (4096 float4 chunks)
    const float4* xg = (const float4*)(x + (size_t)p0 * 256);
    #pragma unroll
    for (int it = 0; it < 16; it++) {
        int idx = it * 256 + t;             // float4 index; 64 per row
        int p = idx >> 6, c4 = idx & 63;
        float4 v = xg[idx];
        ushort4 b; b.x = f2bf(v.x); b.y = f2bf(v.y); b.z = f2bf(v.z); b.w = f2bf(v.w);
        int bcol = (c4 * 8) ^ ((p & 7) << 4);
        *(ushort4*)((char*)xs + p * 512 + bcol) = b;
    }
    // stage W1fT (already bf16): 4096 x 8B chunks (64 rows x 64 chunks)
    const ushort4* wg = (const ushort4*)w1t;
    #pragma unroll
    for (int it = 0; it < 16; it++) {
        int idx = it * 256 + t;
        int p = idx >> 6, c4 = idx & 63;
        int bcol = (c4 * 8) ^ ((p & 7) << 4);
        *(ushort4*)((char*)w1s + p * 512 + bcol) = wg[idx];
    }
    __syncthreads();

    const int wv = t >> 6, ln = t & 63;
    const int r16 = ln & 15, g = ln >> 4;
    const int prow = wv * 16 + r16;

    f32x4 acc[4];
    #pragma unroll
    for (int dt = 0; dt < 4; dt++) {
        float bv = b1f[dt * 16 + r16];
        acc[dt] = (f32x4){bv, bv, bv, bv};
    }
    #pragma unroll
    for (int ks = 0; ks < 8; ks++) {
        int bcA = (ks * 64 + g * 16) ^ ((r16 & 7) << 4);
        bf16x8 av = *(const bf16x8*)((const char*)xs + prow * 512 + bcA);
        #pragma unroll
        for (int dt = 0; dt < 4; dt++) {
            int drow = dt * 16 + r16;                 // drow&7 == r16&7
            bf16x8 bv = *(const bf16x8*)((const char*)w1s + drow * 512 + bcA);
            acc[dt] = __builtin_amdgcn_mfma_f32_16x16x32_bf16(av, bv, acc[dt], 0, 0, 0);
        }
    }
    // epilogue: relu -> bf16 -> h[px][64]
    #pragma unroll
    for (int dt = 0; dt < 4; dt++) {
        #pragma unroll
        for (int r = 0; r < 4; r++) {
            int px = p0 + wv * 16 + g * 4 + r;        // C/D: row=(l>>4)*4+reg, col=l&15
            h[(size_t)px * 64 + dt * 16 + r16] = f2bf(fmaxf(acc[dt][r], 0.f));
        }
    }
}

// GEMM2: ker[p][e] = h[p][d] * W2[d][e] + b2[e], bf16 MFMA.
// Block = 64 pixels, 4 waves; wave owns 16 px x 144 e (9 e-tiles).
__global__ __launch_bounds__(256) void gemm2_kernel(
        const ushort* __restrict__ h, const void* __restrict__ ws,
        const float* __restrict__ b2, float* __restrict__ ker) {
    __shared__ __align__(16) ushort hs[64 * 64];     // 8 KB, 128 B rows
    __shared__ __align__(16) ushort w2s[144 * 64];   // 18 KB
    const int t = threadIdx.x;
    const int p0 = blockIdx.x * 64;
    const ushort* w2t = (const ushort*)ws + 16384;

    // 64 rows x 16 chunks(8B) = 1024 chunks
    const ushort4* hg = (const ushort4*)(h + (size_t)p0 * 64);
    #pragma unroll
    for (int it = 0; it < 4; it++) {
        int idx = it * 256 + t;
        int p = idx >> 4, c4 = idx & 15;
        int bcol = (c4 * 8) ^ ((p & 7) << 4);
        *(ushort4*)((char*)hs + p * 128 + bcol) = hg[idx];
    }
    // 144 rows x 16 chunks = 2304 chunks
    const ushort4* wg = (const ushort4*)w2t;
    #pragma unroll
    for (int it = 0; it < 9; it++) {
        int idx = it * 256 + t;
        int p = idx >> 4, c4 = idx & 15;
        int bcol = (c4 * 8) ^ ((p & 7) << 4);
        *(ushort4*)((char*)w2s + p * 128 + bcol) = wg[idx];
    }
    __syncthreads();

    const int wv = t >> 6, ln = t & 63;
    const int r16 = ln & 15, g = ln >> 4;

    f32x4 acc[9];
    #pragma unroll
    for (int et = 0; et < 9; et++) {
        float bv = b2[et * 16 + r16];
        acc[et] = (f32x4){bv, bv, bv, bv};
    }
    #pragma unroll
    for (int ks = 0; ks < 2; ks++) {
        int bcA = (ks * 64 + g * 16) ^ ((r16 & 7) << 4);
        bf16x8 av = *(const bf16x8*)((const char*)hs + (wv * 16 + r16) * 128 + bcA);
        #pragma unroll
        for (int et = 0; et < 9; et++) {
            int erow = et * 16 + r16;                 // erow&7 == r16&7
            bf16x8 bv = *(const bf16x8*)((const char*)w2s + erow * 128 + bcA);
            acc[et] = __builtin_amdgcn_mfma_f32_16x16x32_bf16(av, bv, acc[et], 0, 0, 0);
        }
    }
    #pragma unroll
    for (int et = 0; et < 9; et++) {
        #pragma unroll
        for (int r = 0; r < 4; r++) {
            int px = p0 + wv * 16 + g * 4 + r;
            ker[(size_t)px * 144 + et * 16 + r16] = acc[et][r];
        }
    }
}

// Involution: one block = 4 pixels (one per wave), lane covers 4 channels (float4).
__global__ __launch_bounds__(256) void invol_kernel(
        const float* __restrict__ x, const float* __restrict__ ker,
        float* __restrict__ out) {
    __shared__ float ks[4 * 144];
    const int t = threadIdx.x;
    const int p0 = blockIdx.x * 4;
    for (int idx = t; idx < 576; idx += 256)
        ks[idx] = ker[(size_t)p0 * 144 + idx];
    __syncthreads();

    const int wave = t >> 6, lane = t & 63;
    const int pix = p0 + wave;
    const int bi = pix >> 6;     // b*64 + i
    const int j  = pix & 63;
    const int i  = bi & 63;

    float4 o = {0.f, 0.f, 0.f, 0.f};
    const float* kp = ks + wave * 144 + (lane & 3) * 4;
    #pragma unroll
    for (int k = 0; k < 9; k++) {
        const int di = k / 3 - 1, dj = k % 3 - 1;
        const int row = i + di, col = j + dj;
        float4 xv = {0.f, 0.f, 0.f, 0.f};
        if ((unsigned)row < 64u && (unsigned)col < 64u) {
            xv = ((const float4*)x)[(size_t)((bi + di) * 64 + col) * 64 + lane];
        }
        float4 kv = *(const float4*)(kp + k * 16);
        o.x += kv.x * xv.x;
        o.y += kv.y * xv.y;
        o.z += kv.z * xv.z;
        o.w += kv.w * xv.w;
    }
    ((float4*)out)[(size_t)pix * 64 + lane] = o;
}

extern "C" void kernel_launch(void* const* d_in, const int* in_sizes, int n_in,
                              void* d_out, int out_size, void* d_ws, size_t ws_size,
                              hipStream_t stream) {
    const float* x     = (const float*)d_in[0];
    const float* W1    = (const float*)d_in[1];
    const float* b1    = (const float*)d_in[2];
    const float* gamma = (const float*)d_in[3];
    const float* beta  = (const float*)d_in[4];
    const float* mmean = (const float*)d_in[5];
    const float* mvar  = (const float*)d_in[6];
    const float* W2    = (const float*)d_in[7];
    const float* b2    = (const float*)d_in[8];

    float* out_main = (float*)d_out;                 // (B,H,W,C)   = 8388608 f32
    float* out_ker  = (float*)d_out + 8388608;       // (B,H,W,144) = 4718592 f32
    ushort* h       = (ushort*)out_main;             // scratch: bf16 [32768][64]

    fold_kernel<<<64, 256, 0, stream>>>(W1, b1, gamma, beta, mmean, mvar, W2, d_ws);
    gemm1_kernel<<<NPIX / 64, 256, 0, stream>>>(x, d_ws, h);
    gemm2_kernel<<<NPIX / 64, 256, 0, stream>>>(h, d_ws, b2, out_ker);
    invol_kernel<<<NPIX / 4, 256, 0, stream>>>(x, out_ker, out_main);
}

// Round 5
// 41.063 us; speedup vs baseline: 4.8662x; 1.0647x over previous
//
#include <hip/hip_runtime.h>

typedef __attribute__((ext_vector_type(8))) short bf16x8;
typedef __attribute__((ext_vector_type(4))) float f32x4;

#define NPIX 32768

// ws byte layout:
//   [0, 32768)      W1fT bf16 [64 d][256 c]   (BN scale folded)
//   [32768, 51200)  W2T  bf16 [144 e][64 d]
//   [51200, 51456)  b1f  f32  [64]            (BN-folded bias)

__device__ __forceinline__ ushort f2bf(float f) {
    union { float f; unsigned u; } v; v.f = f;
    unsigned r = (v.u + 0x7FFFu + ((v.u >> 16) & 1u)) >> 16;  // RNE
    return (ushort)r;
}

__global__ __launch_bounds__(256) void fold_kernel(
        const float* __restrict__ W1, const float* __restrict__ b1,
        const float* __restrict__ gamma, const float* __restrict__ beta,
        const float* __restrict__ mean, const float* __restrict__ var,
        const float* __restrict__ W2, void* __restrict__ ws) {
    ushort* w1t = (ushort*)ws;
    ushort* w2t = (ushort*)ws + 16384;
    float*  b1f = (float*)((char*)ws + 51200);
    int tid = blockIdx.x * 256 + threadIdx.x;
    if (tid < 16384) {
        int d = tid >> 8, c = tid & 255;
        float scale = gamma[d] * rsqrtf(var[d] + 1e-3f);
        w1t[tid] = f2bf(W1[c * 64 + d] * scale);       // W1fT[d][c]
    }
    if (tid < 9216) {
        int e = tid >> 6, d = tid & 63;
        w2t[tid] = f2bf(W2[d * 144 + e]);              // W2T[e][d]
    }
    if (tid < 64) {
        float scale = gamma[tid] * rsqrtf(var[tid] + 1e-3f);
        b1f[tid] = (b1[tid] - mean[tid]) * scale + beta[tid];
    }
}

// Fused kernel-generation: ker[p][e] = (relu(BN(x[p]·W1))·W2 + b2)[e]
// Block = 128 px, 512 threads (8 waves); wave owns 16 px.
// LDS (114 KB): xs 64 KB (aliased by hs 16 KB after GEMM1) | w1s 32 KB | w2s 18 KB
__global__ __launch_bounds__(512) void kergen_kernel(
        const float* __restrict__ x, const void* __restrict__ ws,
        const float* __restrict__ b2, float* __restrict__ ker) {
    __shared__ __align__(16) char smem[116736];
    ushort* xs  = (ushort*)smem;                // [128 rows][512 B], swizzled
    ushort* hs  = (ushort*)smem;                // [128 rows][128 B], aliases xs
    ushort* w1s = (ushort*)(smem + 65536);      // [64 rows][512 B]
    ushort* w2s = (ushort*)(smem + 98304);      // [144 rows][128 B]
    const int t = threadIdx.x;
    const int p0 = blockIdx.x * 128;
    const ushort* w1t = (const ushort*)ws;
    const ushort* w2t = (const ushort*)ws + 16384;
    const float*  b1f = (const float*)((const char*)ws + 51200);

    // stage x tile: f32 -> bf16, XOR-swizzled (8192 float4 chunks)
    const float4* xg = (const float4*)(x + (size_t)p0 * 256);
    #pragma unroll
    for (int it = 0; it < 16; it++) {
        int idx = it * 512 + t;             // 64 chunks per row
        int p = idx >> 6, c4 = idx & 63;
        float4 v = xg[idx];
        ushort4 b; b.x = f2bf(v.x); b.y = f2bf(v.y); b.z = f2bf(v.z); b.w = f2bf(v.w);
        int bcol = (c4 * 8) ^ ((p & 7) << 4);
        *(ushort4*)((char*)xs + p * 512 + bcol) = b;
    }
    // stage W1fT: 4096 x 8B chunks
    const ushort4* w1g = (const ushort4*)w1t;
    #pragma unroll
    for (int it = 0; it < 8; it++) {
        int idx = it * 512 + t;
        int p = idx >> 6, c4 = idx & 63;
        int bcol = (c4 * 8) ^ ((p & 7) << 4);
        *(ushort4*)((char*)w1s + p * 512 + bcol) = w1g[idx];
    }
    // stage W2T: 2304 x 8B chunks (rows of 16 chunks)
    const ushort4* w2g = (const ushort4*)w2t;
    #pragma unroll
    for (int it = 0; it < 5; it++) {
        int idx = it * 512 + t;
        if (idx < 2304) {
            int p = idx >> 4, c4 = idx & 15;
            int bcol = (c4 * 8) ^ ((p & 7) << 4);
            *(ushort4*)((char*)w2s + p * 128 + bcol) = w2g[idx];
        }
    }
    __syncthreads();

    const int wv = t >> 6, ln = t & 63;
    const int r16 = ln & 15, g = ln >> 4;
    const int prow = wv * 16 + r16;

    // ---- GEMM1: 16 px x 64 d per wave ----
    f32x4 acc[4];
    #pragma unroll
    for (int dt = 0; dt < 4; dt++) {
        float bv = b1f[dt * 16 + r16];
        acc[dt] = (f32x4){bv, bv, bv, bv};
    }
    #pragma unroll
    for (int ks = 0; ks < 8; ks++) {
        int bcA = (ks * 64 + g * 16) ^ ((r16 & 7) << 4);
        bf16x8 av = *(const bf16x8*)((const char*)xs + prow * 512 + bcA);
        #pragma unroll
        for (int dt = 0; dt < 4; dt++) {
            int drow = dt * 16 + r16;                 // drow&7 == r16&7
            bf16x8 bv = *(const bf16x8*)((const char*)w1s + drow * 512 + bcA);
            acc[dt] = __builtin_amdgcn_mfma_f32_16x16x32_bf16(av, bv, acc[dt], 0, 0, 0);
        }
    }
    __syncthreads();   // xs dead; hs aliases it

    // relu -> bf16 -> hs (swizzled LDS, consistent with read below)
    #pragma unroll
    for (int dt = 0; dt < 4; dt++) {
        #pragma unroll
        for (int r = 0; r < 4; r++) {
            int pxl = wv * 16 + g * 4 + r;            // C/D: row=(l>>4)*4+reg, col=l&15
            int bcol = ((dt * 16 + r16) * 2) ^ ((pxl & 7) << 4);
            *(ushort*)((char*)hs + pxl * 128 + bcol) = f2bf(fmaxf(acc[dt][r], 0.f));
        }
    }
    __syncthreads();

    // ---- GEMM2: 16 px x 144 e per wave ----
    f32x4 acc2[9];
    #pragma unroll
    for (int et = 0; et < 9; et++) {
        float bv = b2[et * 16 + r16];
        acc2[et] = (f32x4){bv, bv, bv, bv};
    }
    #pragma unroll
    for (int ks = 0; ks < 2; ks++) {
        int bcA = (ks * 64 + g * 16) ^ ((r16 & 7) << 4);
        bf16x8 av = *(const bf16x8*)((const char*)hs + prow * 128 + bcA);
        #pragma unroll
        for (int et = 0; et < 9; et++) {
            int erow = et * 16 + r16;                 // erow&7 == r16&7
            bf16x8 bv = *(const bf16x8*)((const char*)w2s + erow * 128 + bcA);
            acc2[et] = __builtin_amdgcn_mfma_f32_16x16x32_bf16(av, bv, acc2[et], 0, 0, 0);
        }
    }
    #pragma unroll
    for (int et = 0; et < 9; et++) {
        #pragma unroll
        for (int r = 0; r < 4; r++) {
            int px = p0 + wv * 16 + g * 4 + r;
            ker[(size_t)px * 144 + et * 16 + r16] = acc2[et][r];
        }
    }
}

// Involution: one block = 4 pixels (one per wave), lane covers 4 channels (float4).
__global__ __launch_bounds__(256) void invol_kernel(
        const float* __restrict__ x, const float* __restrict__ ker,
        float* __restrict__ out) {
    __shared__ float ks[4 * 144];
    const int t = threadIdx.x;
    const int p0 = blockIdx.x * 4;
    const float* kg = ker + (size_t)p0 * 144;
    for (int idx = t; idx < 576; idx += 256)
        ks[idx] = __builtin_nontemporal_load(&kg[idx]);   // ker read exactly once
    __syncthreads();

    const int wave = t >> 6, lane = t & 63;
    const int pix = p0 + wave;
    const int bi = pix >> 6;     // b*64 + i
    const int j  = pix & 63;
    const int i  = bi & 63;

    f32x4 o = {0.f, 0.f, 0.f, 0.f};
    const float* kp = ks + wave * 144 + (lane & 3) * 4;
    #pragma unroll
    for (int k = 0; k < 9; k++) {
        const int di = k / 3 - 1, dj = k % 3 - 1;
        const int row = i + di, col = j + dj;
        f32x4 xv = {0.f, 0.f, 0.f, 0.f};
        if ((unsigned)row < 64u && (unsigned)col < 64u) {
            xv = ((const f32x4*)x)[(size_t)((bi + di) * 64 + col) * 64 + lane];
        }
        const f32x4 kv = *(const f32x4*)(kp + k * 16);
        o += kv * xv;
    }
    __builtin_nontemporal_store(o, &((f32x4*)out)[(size_t)pix * 64 + lane]);
}

extern "C" void kernel_launch(void* const* d_in, const int* in_sizes, int n_in,
                              void* d_out, int out_size, void* d_ws, size_t ws_size,
                              hipStream_t stream) {
    const float* x     = (const float*)d_in[0];
    const float* W1    = (const float*)d_in[1];
    const float* b1    = (const float*)d_in[2];
    const float* gamma = (const float*)d_in[3];
    const float* beta  = (const float*)d_in[4];
    const float* mmean = (const float*)d_in[5];
    const float* mvar  = (const float*)d_in[6];
    const float* W2    = (const float*)d_in[7];
    const float* b2    = (const float*)d_in[8];

    float* out_main = (float*)d_out;                 // (B,H,W,C)   = 8388608 f32
    float* out_ker  = (float*)d_out + 8388608;       // (B,H,W,144) = 4718592 f32

    fold_kernel<<<64, 256, 0, stream>>>(W1, b1, gamma, beta, mmean, mvar, W2, d_ws);
    kergen_kernel<<<NPIX / 128, 512, 0, stream>>>(x, d_ws, b2, out_ker);
    invol_kernel<<<NPIX / 4, 256, 0, stream>>>(x, out_ker, out_main);
}

// Round 6
// 37.625 us; speedup vs baseline: 5.3108x; 1.0914x over previous
//
#include <hip/hip_runtime.h>

typedef __attribute__((ext_vector_type(8))) short bf16x8;
typedef __attribute__((ext_vector_type(4))) float f32x4;

#define NPIX 32768

// ws byte layout:
//   [0, 32768)      W1fT bf16 [64 d][256 c]   (BN scale folded)
//   [32768, 51200)  W2T  bf16 [144 e][64 d]
//   [51200, 51456)  b1f  f32  [64]            (BN-folded bias)

__device__ __forceinline__ ushort f2bf(float f) {
    union { float f; unsigned u; } v; v.f = f;
    unsigned r = (v.u + 0x7FFFu + ((v.u >> 16) & 1u)) >> 16;  // RNE
    return (ushort)r;
}

__global__ __launch_bounds__(256) void fold_kernel(
        const float* __restrict__ W1, const float* __restrict__ b1,
        const float* __restrict__ gamma, const float* __restrict__ beta,
        const float* __restrict__ mean, const float* __restrict__ var,
        const float* __restrict__ W2, void* __restrict__ ws) {
    ushort* w1t = (ushort*)ws;
    ushort* w2t = (ushort*)ws + 16384;
    float*  b1f = (float*)((char*)ws + 51200);
    int tid = blockIdx.x * 256 + threadIdx.x;
    if (tid < 16384) {
        int d = tid >> 8, c = tid & 255;
        float scale = gamma[d] * rsqrtf(var[d] + 1e-3f);
        w1t[tid] = f2bf(W1[c * 64 + d] * scale);       // W1fT[d][c]
    }
    if (tid < 9216) {
        int e = tid >> 6, d = tid & 63;
        w2t[tid] = f2bf(W2[d * 144 + e]);              // W2T[e][d]
    }
    if (tid < 64) {
        float scale = gamma[tid] * rsqrtf(var[tid] + 1e-3f);
        b1f[tid] = (b1[tid] - mean[tid]) * scale + beta[tid];
    }
}

// Fully fused: GEMM1 -> ReLU -> GEMM2 -> ker store + involution.
// Block = 128 px = 2 image rows (H=64, W=64; 2|64 so no batch straddle).
// 512 threads (8 waves); wave owns 16 px end-to-end (hs and ks are wave-private).
// LDS phases (116736 B):
//   A: xs [128][512B] @0 (64K) | w1s [64][512B] @65536 (32K) | w2s [144][128B] @98304 (18K)
//   B: hs [128][128B] @0 (aliases dead xs)
//   C: ks f32 [128][148] @0 (75776 B, aliases dead xs+w1s)
__global__ __launch_bounds__(512) void fused_kernel(
        const float* __restrict__ x, const void* __restrict__ ws,
        const float* __restrict__ b2, float* __restrict__ ker,
        float* __restrict__ out) {
    __shared__ __align__(16) char smem[116736];
    ushort* xs  = (ushort*)smem;                // [128 rows][512 B], swizzled
    ushort* hs  = (ushort*)smem;                // [128 rows][128 B]
    float*  ks  = (float*)smem;                 // [128][148] f32
    ushort* w1s = (ushort*)(smem + 65536);      // [64 rows][512 B]
    ushort* w2s = (ushort*)(smem + 98304);      // [144 rows][128 B]
    const int t = threadIdx.x;
    const int p0 = blockIdx.x * 128;
    const ushort* w1t = (const ushort*)ws;
    const ushort* w2t = (const ushort*)ws + 16384;
    const float*  b1f = (const float*)((const char*)ws + 51200);

    // ---- stage x tile: f32 -> bf16, XOR-swizzled (8192 float4 chunks) ----
    const float4* xg = (const float4*)(x + (size_t)p0 * 256);
    #pragma unroll
    for (int it = 0; it < 16; it++) {
        int idx = it * 512 + t;             // 64 chunks per row
        int p = idx >> 6, c4 = idx & 63;
        float4 v = xg[idx];
        ushort4 b; b.x = f2bf(v.x); b.y = f2bf(v.y); b.z = f2bf(v.z); b.w = f2bf(v.w);
        int bcol = (c4 * 8) ^ ((p & 7) << 4);
        *(ushort4*)((char*)xs + p * 512 + bcol) = b;
    }
    // stage W1fT: 4096 x 8B chunks
    const ushort4* w1g = (const ushort4*)w1t;
    #pragma unroll
    for (int it = 0; it < 8; it++) {
        int idx = it * 512 + t;
        int p = idx >> 6, c4 = idx & 63;
        int bcol = (c4 * 8) ^ ((p & 7) << 4);
        *(ushort4*)((char*)w1s + p * 512 + bcol) = w1g[idx];
    }
    // stage W2T: 2304 x 8B chunks (rows of 16 chunks)
    const ushort4* w2g = (const ushort4*)w2t;
    #pragma unroll
    for (int it = 0; it < 5; it++) {
        int idx = it * 512 + t;
        if (idx < 2304) {
            int p = idx >> 4, c4 = idx & 15;
            int bcol = (c4 * 8) ^ ((p & 7) << 4);
            *(ushort4*)((char*)w2s + p * 128 + bcol) = w2g[idx];
        }
    }
    __syncthreads();

    const int wv = t >> 6, ln = t & 63;
    const int r16 = ln & 15, g = ln >> 4;
    const int prow = wv * 16 + r16;

    // ---- GEMM1: 16 px x 64 d per wave ----
    f32x4 acc[4];
    #pragma unroll
    for (int dt = 0; dt < 4; dt++) {
        float bv = b1f[dt * 16 + r16];
        acc[dt] = (f32x4){bv, bv, bv, bv};
    }
    #pragma unroll
    for (int kk = 0; kk < 8; kk++) {
        int bcA = (kk * 64 + g * 16) ^ ((r16 & 7) << 4);
        bf16x8 av = *(const bf16x8*)((const char*)xs + prow * 512 + bcA);
        #pragma unroll
        for (int dt = 0; dt < 4; dt++) {
            int drow = dt * 16 + r16;                 // drow&7 == r16&7
            bf16x8 bv = *(const bf16x8*)((const char*)w1s + drow * 512 + bcA);
            acc[dt] = __builtin_amdgcn_mfma_f32_16x16x32_bf16(av, bv, acc[dt], 0, 0, 0);
        }
    }
    __syncthreads();   // xs dead; hs aliases it

    // relu -> bf16 -> hs (swizzled, wave-private rows)
    #pragma unroll
    for (int dt = 0; dt < 4; dt++) {
        #pragma unroll
        for (int r = 0; r < 4; r++) {
            int pxl = wv * 16 + g * 4 + r;            // C/D: row=(l>>4)*4+reg, col=l&15
            int bcol = ((dt * 16 + r16) * 2) ^ ((pxl & 7) << 4);
            *(ushort*)((char*)hs + pxl * 128 + bcol) = f2bf(fmaxf(acc[dt][r], 0.f));
        }
    }
    __syncthreads();

    // ---- GEMM2: 16 px x 144 e per wave ----
    f32x4 acc2[9];
    #pragma unroll
    for (int et = 0; et < 9; et++) {
        float bv = b2[et * 16 + r16];
        acc2[et] = (f32x4){bv, bv, bv, bv};
    }
    #pragma unroll
    for (int kk = 0; kk < 2; kk++) {
        int bcA = (kk * 64 + g * 16) ^ ((r16 & 7) << 4);
        bf16x8 av = *(const bf16x8*)((const char*)hs + prow * 128 + bcA);
        #pragma unroll
        for (int et = 0; et < 9; et++) {
            int erow = et * 16 + r16;                 // erow&7 == r16&7
            bf16x8 bv = *(const bf16x8*)((const char*)w2s + erow * 128 + bcA);
            acc2[et] = __builtin_amdgcn_mfma_f32_16x16x32_bf16(av, bv, acc2[et], 0, 0, 0);
        }
    }
    __syncthreads();   // hs/w1s reads done; ks may alias

    // ---- ker: global (output) + LDS ks for the involution phase ----
    #pragma unroll
    for (int et = 0; et < 9; et++) {
        #pragma unroll
        for (int r = 0; r < 4; r++) {
            int pxl = wv * 16 + g * 4 + r;
            int e = et * 16 + r16;
            __builtin_nontemporal_store(acc2[et][r], &ker[(size_t)(p0 + pxl) * 144 + e]);
            ks[pxl * 148 + e] = acc2[et][r];   // row stride 148: 2-way bank alias = free
        }
    }
    __syncthreads();

    // ---- involution: wave owns its 16 px; lane = channel chunk (4 ch) ----
    const f32x4* xv4 = (const f32x4*)x;
    #pragma unroll 2
    for (int pp = 0; pp < 16; pp++) {
        const int pl = wv * 16 + pp;
        const int pix = p0 + pl;
        const int bi = pix >> 6;     // b*64 + i
        const int j  = pix & 63;
        const int i  = bi & 63;
        const float* kp = ks + pl * 148 + (ln & 3) * 4;
        f32x4 o = {0.f, 0.f, 0.f, 0.f};
        #pragma unroll
        for (int k = 0; k < 9; k++) {
            const int di = k / 3 - 1, dj = k % 3 - 1;
            const int row = i + di, col = j + dj;
            f32x4 xv = {0.f, 0.f, 0.f, 0.f};
            if ((unsigned)row < 64u && (unsigned)col < 64u)
                xv = xv4[(size_t)((bi + di) * 64 + col) * 64 + ln];
            const f32x4 kv = *(const f32x4*)(kp + k * 16);
            o += kv * xv;
        }
        __builtin_nontemporal_store(o, &((f32x4*)out)[(size_t)pix * 64 + ln]);
    }
}

extern "C" void kernel_launch(void* const* d_in, const int* in_sizes, int n_in,
                              void* d_out, int out_size, void* d_ws, size_t ws_size,
                              hipStream_t stream) {
    const float* x     = (const float*)d_in[0];
    const float* W1    = (const float*)d_in[1];
    const float* b1    = (const float*)d_in[2];
    const float* gamma = (const float*)d_in[3];
    const float* beta  = (const float*)d_in[4];
    const float* mmean = (const float*)d_in[5];
    const float* mvar  = (const float*)d_in[6];
    const float* W2    = (const float*)d_in[7];
    const float* b2    = (const float*)d_in[8];

    float* out_main = (float*)d_out;                 // (B,H,W,C)   = 8388608 f32
    float* out_ker  = (float*)d_out + 8388608;       // (B,H,W,144) = 4718592 f32

    fold_kernel<<<64, 256, 0, stream>>>(W1, b1, gamma, beta, mmean, mvar, W2, d_ws);
    fused_kernel<<<NPIX / 128, 512, 0, stream>>>(x, d_ws, b2, out_ker, out_main);
}